// Round 20
// baseline (63.207 us; speedup 1.0000x reference)
//
#include <hip/hip_runtime.h>

#define BB 16
#define TV 256
#define TS 32
#define DD 512

typedef float    floatx4  __attribute__((ext_vector_type(4)));
typedef short    short8   __attribute__((ext_vector_type(8)));
typedef unsigned short ushort8 __attribute__((ext_vector_type(8)));

#define TANH_SCALE 2.885390082f   // 2*log2(e): tanh(y)=1-2/(exp2(2y*log2e)+1)

static __device__ __forceinline__ unsigned short f2bf(float f) {
    unsigned int u = __float_as_uint(f);
    u += 0x7FFFu + ((u >> 16) & 1u);   // RNE (inputs finite)
    return (unsigned short)(u >> 16);
}

#define GLL(srcp, dstp)                                                        \
    __builtin_amdgcn_global_load_lds(                                          \
        (const __attribute__((address_space(1))) void*)(srcp),                 \
        (__attribute__((address_space(3))) void*)(dstp), 16, 0, 0)

// ---------------------------------------------------------------------------
// Pass 1: convert f32 -> bf16 (~4us) + wsum side-task.
// ---------------------------------------------------------------------------
__global__ __launch_bounds__(256) void ta_convert(
    const float* __restrict__ video, const float* __restrict__ sent,
    const float* __restrict__ w1,    const float* __restrict__ w2,
    unsigned short* __restrict__ vb, unsigned short* __restrict__ sb,
    unsigned short* __restrict__ w1b, unsigned short* __restrict__ w2b,
    const float* __restrict__ wt,    float* __restrict__ wsum)
{
    const int NV = BB * TV * DD, NS = BB * TS * DD, NW = DD * DD;
    const int t = threadIdx.x;
    if (blockIdx.x == 0 && t < 64) {
        float v = 0.f;
        for (int i = t; i < DD; i += 64) v += wt[i];
        for (int off = 32; off; off >>= 1) v += __shfl_down(v, off);
        if (t == 0) wsum[0] = v;
    }
    const int base = (blockIdx.x * 256 + t) * 8;
    const float* src; unsigned short* dst; int off;
    if      (base < NV)           { src = video; dst = vb;  off = base; }
    else if (base < NV + NS)      { src = sent;  dst = sb;  off = base - NV; }
    else if (base < NV + NS + NW) { src = w1;    dst = w1b; off = base - NV - NS; }
    else                          { src = w2;    dst = w2b; off = base - NV - NS - NW; }
    const float4 a = *(const float4*)(src + off);
    const float4 b = *(const float4*)(src + off + 4);
    ushort8 o;
    o[0] = f2bf(a.x); o[1] = f2bf(a.y); o[2] = f2bf(a.z); o[3] = f2bf(a.w);
    o[4] = f2bf(b.x); o[5] = f2bf(b.y); o[6] = f2bf(b.z); o[7] = f2bf(b.w);
    *(ushort8*)(dst + off) = o;
}

// ---------------------------------------------------------------------------
// Pass 2: small g2 GEMM -> E2 = bf16(exp2(clamp(z2))), plain [b*32+s][d]
// row-major (512x512 bf16, 512KB). 64 blocks, proven tile structure.
// ---------------------------------------------------------------------------
__global__ __launch_bounds__(256) void ta_g2(
    const unsigned short* __restrict__ sb, const unsigned short* __restrict__ w2b,
    const float* __restrict__ smask,       unsigned short* __restrict__ tmp2e)
{
    const int t = threadIdx.x;
    const int bid = blockIdx.x;
    const int m0 = (bid & 7) * 64;
    const int n0 = (bid >> 3) * 64;

    __shared__ unsigned short As[2][4096];
    __shared__ unsigned short Bs[2][4096];

    const int lane = t & 63;
    const int wid  = t >> 6;
    const int wm   = wid >> 1, wn = wid & 1;
    const int lr   = lane & 15, kg = lane >> 4;

    const int r0 = t >> 3,          g0c = (t & 7) ^ (r0 & 7);
    const int r1 = (t + 256) >> 3,  g1c = (t & 7) ^ (r1 & 7);
    const unsigned short* a0p = sb  + (size_t)(m0 + r0) * DD + g0c * 8;
    const unsigned short* a1p = sb  + (size_t)(m0 + r1) * DD + g1c * 8;
    const unsigned short* w0p = w2b + (size_t)(n0 + r0) * DD + g0c * 8;
    const unsigned short* w1p = w2b + (size_t)(n0 + r1) * DD + g1c * 8;
    const int l0 = t * 8, l1 = (t + 256) * 8;

#define G2_STAGE(buf, koff) do {                                               \
    GLL(a0p + (koff), &As[buf][l0]); GLL(a1p + (koff), &As[buf][l1]);          \
    GLL(w0p + (koff), &Bs[buf][l0]); GLL(w1p + (koff), &Bs[buf][l1]);          \
  } while (0)

    floatx4 acc[2][2] = {};
    const int ml0 = wm * 32 + lr, ml1 = ml0 + 16;
    const int nl0 = wn * 32 + lr, nl1 = nl0 + 16;
    const int sa0 = ml0 * 64, sa1 = ml1 * 64;
    const int sb0 = nl0 * 64, sb1 = nl1 * 64;
    const int xa = ml0 & 7, xb = nl0 & 7;

    G2_STAGE(0, 0);
    __syncthreads();
    int cur = 0;
    for (int step = 0; step < 8; ++step) {
        if (step < 7) G2_STAGE(cur ^ 1, (step + 1) * 64);
#pragma unroll
        for (int kk = 0; kk < 2; ++kk) {
            const int kc = kk * 4 + kg;
            short8 a0 = *(const short8*)&As[cur][sa0 + ((kc ^ xa) << 3)];
            short8 a1 = *(const short8*)&As[cur][sa1 + ((kc ^ xa) << 3)];
            short8 b0 = *(const short8*)&Bs[cur][sb0 + ((kc ^ xb) << 3)];
            short8 b1 = *(const short8*)&Bs[cur][sb1 + ((kc ^ xb) << 3)];
            acc[0][0] = __builtin_amdgcn_mfma_f32_16x16x32_bf16(a0, b0, acc[0][0], 0, 0, 0);
            acc[0][1] = __builtin_amdgcn_mfma_f32_16x16x32_bf16(a0, b1, acc[0][1], 0, 0, 0);
            acc[1][0] = __builtin_amdgcn_mfma_f32_16x16x32_bf16(a1, b0, acc[1][0], 0, 0, 0);
            acc[1][1] = __builtin_amdgcn_mfma_f32_16x16x32_bf16(a1, b1, acc[1][1], 0, 0, 0);
        }
        __syncthreads();
        cur ^= 1;
    }
#undef G2_STAGE

#pragma unroll
    for (int fm = 0; fm < 2; ++fm)
#pragma unroll
        for (int fn = 0; fn < 2; ++fn)
#pragma unroll
            for (int r = 0; r < 4; ++r) {
                const int m = m0 + wm * 32 + fm * 16 + kg * 4 + r;
                const int n = n0 + wn * 32 + fn * 16 + lr;
                float z = acc[fm][fn][r] * smask[m] * TANH_SCALE;
                z = fminf(fmaxf(z, -30.f), 30.f);
                tmp2e[(size_t)m * DD + n] = f2bf(__builtin_amdgcn_exp2f(z));
            }
}

// ---------------------------------------------------------------------------
// Pass 3: FUSED g1-GEMM + tanh. Block = (b, v-tile of 16), grid 256.
// E1 (16x512) lives only in LDS — the 4MB intermediate is eliminated.
//  GEMM: As[16][512] staged once; Bs dbuf 64x64 tiles; 64 iters (8n x 8k);
//  epilogue per n-iter writes bf16(exp2(clamp(z1))) into swizzled E1 LDS.
//  tanh: thread (v=t>>4, s=t&15) reduces all 512 d for s and s+16,
//  writes out directly (no partials). LDS 80KB -> 2 blocks/CU.
// ---------------------------------------------------------------------------
__global__ __launch_bounds__(256, 2) void ta_fused(
    const unsigned short* __restrict__ vb, const unsigned short* __restrict__ w1b,
    const float* __restrict__ b1,          const float* __restrict__ vmask,
    const float* __restrict__ smask,       const unsigned short* __restrict__ tmp2e,
    const float* __restrict__ wt,          const float* __restrict__ wsum,
    float* __restrict__ out)
{
    __shared__ unsigned short As[16 * 512];   // 16 KB
    __shared__ unsigned short Bs[2][64 * 64]; // 16 KB
    __shared__ unsigned short E1[16 * 512];   // 16 KB
    __shared__ unsigned short E2[32 * 512];   // 32 KB

    const int t   = threadIdx.x;
    const int bid = blockIdx.x;
    const int b   = bid >> 4;
    const int v0  = (bid & 15) << 4;

    // ---- stage As (4x16B/thr) + E2 (8x16B/thr), swizzled via global source
#pragma unroll
    for (int i = 0; i < 4; ++i) {
        const int c = t + 256 * i;                 // 1024 chunks, row = c>>6
        const int row = c >> 6, sc = (c & 63) ^ (row & 7);
        GLL(vb + (size_t)(b * TV + v0 + row) * DD + sc * 8, &As[c * 8]);
    }
#pragma unroll
    for (int i = 0; i < 8; ++i) {
        const int c = t + 256 * i;                 // 2048 chunks, row = c>>6
        const int row = c >> 6, sc = (c & 63) ^ (row & 7);
        GLL(tmp2e + (size_t)(b * TS + row) * DD + sc * 8, &E2[c * 8]);
    }
    // ---- stage Bs[0] for it=0 (n0=0,k0=0)
    {
        const int c0 = t,       br0 = c0 >> 3, w0c = (c0 & 7) ^ (br0 & 7);
        const int c1 = t + 256, br1 = c1 >> 3, w1c = (c1 & 7) ^ (br1 & 7);
        GLL(w1b + (size_t)br0 * DD + w0c * 8, &Bs[0][c0 * 8]);
        GLL(w1b + (size_t)br1 * DD + w1c * 8, &Bs[0][c1 * 8]);
    }
    __syncthreads();

    const int lane = t & 63;
    const int wid  = t >> 6;
    const int lr   = lane & 15, kg = lane >> 4;
    const int brow = wid * 16 + lr;
    const int xb   = brow & 7, xa = lr & 7;
    const int saB  = brow * 64;

    floatx4 acc = {0.f, 0.f, 0.f, 0.f};
    int cur = 0;
    for (int it = 0; it < 64; ++it) {
        if (it < 63) {
            const int nit = it + 1;
            const int nn0 = (nit >> 3) * 64, nk0 = (nit & 7) * 64;
            const int c0 = t,       br0 = c0 >> 3, w0c = (c0 & 7) ^ (br0 & 7);
            const int c1 = t + 256, br1 = c1 >> 3, w1c = (c1 & 7) ^ (br1 & 7);
            GLL(w1b + (size_t)(nn0 + br0) * DD + nk0 + w0c * 8, &Bs[cur ^ 1][c0 * 8]);
            GLL(w1b + (size_t)(nn0 + br1) * DD + nk0 + w1c * 8, &Bs[cur ^ 1][c1 * 8]);
        }
        const int kbase = (it & 7) * 64;           // element offset of k0 in As row
#pragma unroll
        for (int kk = 0; kk < 2; ++kk) {
            const int kc = kk * 4 + kg;
            short8 a = *(const short8*)&As[lr * DD + kbase + ((kc ^ xa) << 3)];
            short8 bf = *(const short8*)&Bs[cur][saB + ((kc ^ xb) << 3)];
            acc = __builtin_amdgcn_mfma_f32_16x16x32_bf16(a, bf, acc, 0, 0, 0);
        }
        if ((it & 7) == 7) {
            const int n0 = (it >> 3) * 64;
#pragma unroll
            for (int r = 0; r < 4; ++r) {
                const int m = kg * 4 + r;          // 0..15 (v row in tile)
                const int n = n0 + wid * 16 + lr;  // 0..511 (d)
                const float mk = vmask[b * TV + v0 + m] * TANH_SCALE;
                float z = (acc[r] + b1[n]) * mk;
                z = fminf(fmaxf(z, -30.f), 30.f);
                const float e = __builtin_amdgcn_exp2f(z);
                E1[m * DD + (((n >> 3) ^ (m & 7)) << 3) + (n & 7)] = f2bf(e);
            }
            acc = (floatx4){0.f, 0.f, 0.f, 0.f};
        }
        __syncthreads();
        cur ^= 1;
    }

    // ---- tanh phase: thread (v = t>>4, s = t&15; also s+16)
    const int s2 = t & 15;
    const int v  = t >> 4;
    const int xv = v & 7, xl = s2 & 7, xh = (s2 + 16) & 7;
    const unsigned short* e1p = E1 + v * DD;
    const unsigned short* e2l = E2 + s2 * DD;
    const unsigned short* e2h = E2 + (s2 + 16) * DD;

    float accL = 0.f, accH = 0.f;
#pragma unroll 8
    for (int c = 0; c < 64; ++c) {
        ushort8 e1 = *(const ushort8*)&e1p[(c ^ xv) << 3];
        ushort8 al = *(const ushort8*)&e2l[(c ^ xl) << 3];
        ushort8 ah = *(const ushort8*)&e2h[(c ^ xh) << 3];
        floatx4 wA = *(const floatx4*)(wt + c * 8);
        floatx4 wB = *(const floatx4*)(wt + c * 8 + 4);
#pragma unroll
        for (int j = 0; j < 8; ++j) {
            const float w  = (j < 4) ? wA[j] : wB[j - 4];
            const float x1 = __uint_as_float((unsigned)e1[j] << 16);
            const float yl = __uint_as_float((unsigned)al[j] << 16);
            const float yh = __uint_as_float((unsigned)ah[j] << 16);
            accL = fmaf(w, __builtin_amdgcn_rcpf(fmaf(x1, yl, 1.f)), accL);
            accH = fmaf(w, __builtin_amdgcn_rcpf(fmaf(x1, yh, 1.f)), accH);
        }
    }

    const float ws = wsum[0];
    const float vm = vmask[b * TV + v0 + v];
    const float pmL = vm * smask[b * TS + s2];
    const float pmH = vm * smask[b * TS + s2 + 16];
    float* orow = out + ((size_t)(b * TV + v0 + v)) * TS;
    orow[s2]      = pmL * (ws - 2.f * accL);
    orow[s2 + 16] = pmH * (ws - 2.f * accH);
}

// ---------------------------------------------------------------------------
extern "C" void kernel_launch(void* const* d_in, const int* in_sizes, int n_in,
                              void* d_out, int out_size, void* d_ws, size_t ws_size,
                              hipStream_t stream)
{
    const float* video = (const float*)d_in[0];
    const float* vmask = (const float*)d_in[1];
    const float* sent  = (const float*)d_in[2];
    const float* smask = (const float*)d_in[3];
    const float* w1    = (const float*)d_in[4];
    const float* b1    = (const float*)d_in[5];
    const float* w2    = (const float*)d_in[6];
    const float* wt    = (const float*)d_in[7];
    float* out = (float*)d_out;

    const size_t NV = (size_t)BB * TV * DD, NS = (size_t)BB * TS * DD, NW = (size_t)DD * DD;

    unsigned short* tmp2e = (unsigned short*)d_ws;   // 512 KB bf16 (E2 [512][512])
    unsigned short* vb    = tmp2e + NS;              // 4 MB
    unsigned short* sb    = vb + NV;                 // 512 KB
    unsigned short* w1b   = sb + NS;                 // 512 KB
    unsigned short* w2b   = w1b + NW;                // 512 KB
    float* wsum           = (float*)(w2b + NW);      // 4 B

    const int total8 = (int)((NV + NS + 2 * NW) / 8);
    ta_convert<<<dim3(total8 / 256), dim3(256), 0, stream>>>(
        video, sent, w1, w2, vb, sb, w1b, w2b, wt, wsum);
    ta_g2<<<dim3(64), dim3(256), 0, stream>>>(sb, w2b, smask, tmp2e);
    ta_fused<<<dim3(256), dim3(256), 0, stream>>>(
        vb, w1b, b1, vmask, smask, tmp2e, wt, wsum, out);
}